// Round 1
// baseline (3759.416 us; speedup 1.0000x reference)
//
#include <hip/hip_runtime.h>
#include <math.h>

// GNN denoiser: N=32768 nodes, HID=128, L=4 layers.
// Key structure: concat-edge-MLP factorized into node GEMMs A,B + per-edge
// nonlinear 128x128 MVM; symmetric grid graph => aggregate by iterating the
// row-sorted edge list per destination node (no atomics).

#define HIDDEN 128
#define NLAYERS 4

__device__ __forceinline__ float silu_f(float x) {
    return x / (1.f + __expf(-x));
}

// row_ptr[v] = lower_bound(row, v), rows sorted ascending. v in [0, N].
__global__ __launch_bounds__(256) void rowptr_kernel(
    const int* __restrict__ row, int E, int N, int* __restrict__ rp) {
    int v = blockIdx.x * 256 + threadIdx.x;
    if (v > N) return;
    int lo = 0, hi = E;
    while (lo < hi) {
        int mid = (lo + hi) >> 1;
        if (row[mid] < v) lo = mid + 1; else hi = mid;
    }
    rp[v] = lo;
}

// LayerNorm over last dim (128). One wave per node, lane holds 2 elems.
__global__ __launch_bounds__(256) void ln_kernel(
    const float* __restrict__ h, const float* __restrict__ g,
    const float* __restrict__ b, float* __restrict__ hn, int N) {
    int tid = threadIdx.x;
    int wid = tid >> 6, l = tid & 63;
    int v = blockIdx.x * 4 + wid;
    if (v >= N) return;
    const float2* hp = reinterpret_cast<const float2*>(h + (size_t)v * HIDDEN);
    float2 x = hp[l];
    float sum = x.x + x.y;
#pragma unroll
    for (int o = 1; o < 64; o <<= 1) sum += __shfl_xor(sum, o, 64);
    float mu = sum * (1.f / 128.f);
    float d0 = x.x - mu, d1 = x.y - mu;
    float ssq = d0 * d0 + d1 * d1;
#pragma unroll
    for (int o = 1; o < 64; o <<= 1) ssq += __shfl_xor(ssq, o, 64);
    float rs = rsqrtf(ssq * (1.f / 128.f) + 1e-5f);
    float2 gg = reinterpret_cast<const float2*>(g)[l];
    float2 bb = reinterpret_cast<const float2*>(b)[l];
    float2 o2;
    o2.x = d0 * rs * gg.x + bb.x;
    o2.y = d1 * rs * gg.y + bb.y;
    reinterpret_cast<float2*>(hn + (size_t)v * HIDDEN)[l] = o2;
}

// Generic fp32 GEMM: Y[M, ldY](col block cb..cb+127) =
//   act( [X1|X2] @ W(ldW, col offset wOff)^T + bias + resid )
// Block: 256 threads, tile 64 rows x 128 cols, K chunk 32.
__global__ __launch_bounds__(256) void gemm_kernel(
    const float* __restrict__ X1, int K1,
    const float* __restrict__ X2, int K2,
    const float* __restrict__ W, int ldW, int wOff,
    const float* __restrict__ bias,
    const float* __restrict__ resid,   // [M,128] (only for Nout==128 uses)
    float* __restrict__ Y, int ldY,
    int act) {
    __shared__ float Xs[64 * 33];
    __shared__ float Ws[128 * 33];
    int tid = threadIdx.x;
    int tx = tid & 31, ty = tid >> 5;
    int row0 = blockIdx.x * 64;
    int cb = blockIdx.y * 128;
    int K = K1 + K2;
    float acc[8][4];
#pragma unroll
    for (int i = 0; i < 8; ++i)
#pragma unroll
        for (int j = 0; j < 4; ++j) acc[i][j] = 0.f;

    for (int kk0 = 0; kk0 < K; kk0 += 32) {
        const float* Xsrc;
        int ldX, koff;
        if (kk0 < K1) { Xsrc = X1; ldX = K1; koff = kk0; }
        else          { Xsrc = X2; ldX = K2; koff = kk0 - K1; }
        // X tile: 64 rows x 32 k, float4 loads
        {
            int r = tid >> 3, kv = (tid & 7) * 4;
            const float4 a0 = *reinterpret_cast<const float4*>(
                Xsrc + (size_t)(row0 + r) * ldX + koff + kv);
            Xs[r * 33 + kv + 0] = a0.x; Xs[r * 33 + kv + 1] = a0.y;
            Xs[r * 33 + kv + 2] = a0.z; Xs[r * 33 + kv + 3] = a0.w;
            const float4 a1 = *reinterpret_cast<const float4*>(
                Xsrc + (size_t)(row0 + r + 32) * ldX + koff + kv);
            Xs[(r + 32) * 33 + kv + 0] = a1.x; Xs[(r + 32) * 33 + kv + 1] = a1.y;
            Xs[(r + 32) * 33 + kv + 2] = a1.z; Xs[(r + 32) * 33 + kv + 3] = a1.w;
        }
        // W tile: 128 cols(c) x 32 k, scalar coalesced (ldW may be odd, e.g. 257)
        {
            int kv = tid & 31, cbase = tid >> 5;
#pragma unroll
            for (int i = 0; i < 16; ++i) {
                int c = cbase + i * 8;
                Ws[c * 33 + kv] = W[(size_t)(cb + c) * ldW + wOff + kk0 + kv];
            }
        }
        __syncthreads();
#pragma unroll
        for (int kk = 0; kk < 32; ++kk) {
            float xv[8], wv[4];
#pragma unroll
            for (int i = 0; i < 8; ++i) xv[i] = Xs[(ty * 8 + i) * 33 + kk];
#pragma unroll
            for (int j = 0; j < 4; ++j) wv[j] = Ws[(tx + 32 * j) * 33 + kk];
#pragma unroll
            for (int i = 0; i < 8; ++i)
#pragma unroll
                for (int j = 0; j < 4; ++j) acc[i][j] += xv[i] * wv[j];
        }
        __syncthreads();
    }
#pragma unroll
    for (int i = 0; i < 8; ++i) {
        int row = row0 + ty * 8 + i;
#pragma unroll
        for (int j = 0; j < 4; ++j) {
            int c = tx + 32 * j;
            float val = acc[i][j];
            if (bias) val += bias[cb + c];
            if (resid) val += resid[(size_t)row * HIDDEN + c];
            if (act) val = silu_f(val);
            Y[(size_t)row * ldY + cb + c] = val;
        }
    }
}

// Edge MLP + mean aggregation. One wave per destination node v.
// m_aggr[v] = mean_{u in N(v)} silu( silu(A[u]+B[v]+dist*wd+eb1) @ eW2^T + eb2 )
// eW2 staged transposed+swizzled in LDS (conflict-free read & write).
__global__ __launch_bounds__(256) void edge_kernel(
    const float* __restrict__ A, const float* __restrict__ B,
    const float* __restrict__ gc, const int* __restrict__ col,
    const int* __restrict__ rp,
    const float* __restrict__ eW1l, const float* __restrict__ eb1l,
    const float* __restrict__ eW2l, const float* __restrict__ eb2l,
    float* __restrict__ mag, int N) {
    __shared__ float W2T[128 * 128];   // W2T[k][j^ (k&31)] = eW2[j][k]
    int tid = threadIdx.x;
#pragma unroll
    for (int i = 0; i < 64; ++i) {
        int idx = tid + i * 256;       // idx = j*128 + k (coalesced global read)
        int j = idx >> 7, k = idx & 127;
        W2T[k * 128 + (j ^ (k & 31))] = eW2l[idx];
    }
    __syncthreads();
    int wid = tid >> 6, l = tid & 63;
    int v = blockIdx.x * 4 + wid;
    if (v >= N) return;

    float bb0 = B[(size_t)v * HIDDEN + l] + eb1l[l];
    float bb1 = B[(size_t)v * HIDDEN + l + 64] + eb1l[l + 64];
    float wd0 = eW1l[l * 257 + 256];
    float wd1 = eW1l[(l + 64) * 257 + 256];
    float e20 = eb2l[l], e21 = eb2l[l + 64];
    float gx = gc[(size_t)v * 3], gy = gc[(size_t)v * 3 + 1], gz = gc[(size_t)v * 3 + 2];
    int s = rp[v], e = rp[v + 1];
    float agg0 = 0.f, agg1 = 0.f;

    for (int t = s; t < e; ++t) {
        int u = col[t];
        float dx = gc[(size_t)u * 3] - gx;
        float dy = gc[(size_t)u * 3 + 1] - gy;
        float dz = gc[(size_t)u * 3 + 2] - gz;
        float dist = sqrtf(dx * dx + dy * dy + dz * dz);
        float p0 = A[(size_t)u * HIDDEN + l] + bb0 + dist * wd0;
        float p1 = A[(size_t)u * HIDDEN + l + 64] + bb1 + dist * wd1;
        float m1a = silu_f(p0);
        float m1b = silu_f(p1);
        float macc0 = e20, macc1 = e21;
#pragma unroll
        for (int k = 0; k < 64; ++k) {
            float sa = __int_as_float(
                __builtin_amdgcn_readlane(__float_as_int(m1a), k));
            macc0 += sa * W2T[k * 128 + (l ^ (k & 31))];
            macc1 += sa * W2T[k * 128 + ((l + 64) ^ (k & 31))];
        }
#pragma unroll
        for (int k = 0; k < 64; ++k) {
            float sb = __int_as_float(
                __builtin_amdgcn_readlane(__float_as_int(m1b), k));
            int kk = k + 64;
            macc0 += sb * W2T[kk * 128 + (l ^ (kk & 31))];
            macc1 += sb * W2T[kk * 128 + ((l + 64) ^ (kk & 31))];
        }
        agg0 += silu_f(macc0);
        agg1 += silu_f(macc1);
    }
    float cnt = (float)(e - s);
    float ic = cnt > 0.f ? 1.f / cnt : 0.f;
    mag[(size_t)v * HIDDEN + l] = agg0 * ic;
    mag[(size_t)v * HIDDEN + l + 64] = agg1 * ic;
}

extern "C" void kernel_launch(void* const* d_in, const int* in_sizes, int n_in,
                              void* d_out, int out_size, void* d_ws, size_t ws_size,
                              hipStream_t stream) {
    const float* y     = (const float*)d_in[0];
    const float* gc    = (const float*)d_in[1];
    const int*   eidx  = (const int*)d_in[2];
    const float* W_in  = (const float*)d_in[3];
    const float* b_in  = (const float*)d_in[4];
    const float* gam   = (const float*)d_in[5];
    const float* bet   = (const float*)d_in[6];
    const float* eW1   = (const float*)d_in[7];
    const float* eb1   = (const float*)d_in[8];
    const float* eW2   = (const float*)d_in[9];
    const float* eb2   = (const float*)d_in[10];
    const float* nW1   = (const float*)d_in[11];
    const float* nb1   = (const float*)d_in[12];
    const float* nW2   = (const float*)d_in[13];
    const float* nb2   = (const float*)d_in[14];
    const float* W_out = (const float*)d_in[15];
    const float* b_out = (const float*)d_in[16];

    const int CODE = in_sizes[16];          // 1024 (b_out)
    const int M = in_sizes[0] / CODE;       // 32768 nodes
    const int E = in_sizes[2] / 2;

    float* out = (float*)d_out;

    float* buf_h  = (float*)d_ws;                       // h; later m_aggr; later h_new
    float* buf_hn = buf_h  + (size_t)M * HIDDEN;        // hn
    float* buf_A  = buf_hn + (size_t)M * HIDDEN;        // A; later t
    float* buf_B  = buf_A  + (size_t)M * HIDDEN;        // B
    int*   row_ptr = (int*)(buf_B + (size_t)M * HIDDEN);

    const int* row  = eidx;
    const int* colA = eidx + E;

    rowptr_kernel<<<dim3((M + 1 + 255) / 256), 256, 0, stream>>>(row, E, M, row_ptr);

    // h = y @ W_in^T + b_in   [M,1024]x[1024,128]
    gemm_kernel<<<dim3(M / 64, 1), 256, 0, stream>>>(
        y, CODE, nullptr, 0, W_in, CODE, 0, b_in, nullptr, buf_h, HIDDEN, 0);

    for (int l = 0; l < NLAYERS; ++l) {
        const float* eW1l = eW1 + (size_t)l * HIDDEN * 257;
        const float* eb1l = eb1 + (size_t)l * HIDDEN;
        const float* eW2l = eW2 + (size_t)l * HIDDEN * HIDDEN;
        const float* eb2l = eb2 + (size_t)l * HIDDEN;
        const float* nW1l = nW1 + (size_t)l * HIDDEN * 256;
        const float* nb1l = nb1 + (size_t)l * HIDDEN;
        const float* nW2l = nW2 + (size_t)l * HIDDEN * HIDDEN;
        const float* nb2l = nb2 + (size_t)l * HIDDEN;

        // hn = LN(h)
        ln_kernel<<<dim3(M / 4), 256, 0, stream>>>(
            buf_h, gam + (size_t)l * HIDDEN, bet + (size_t)l * HIDDEN, buf_hn, M);

        // A = hn @ eW1[:, :128]^T ; B = hn @ eW1[:,128:256]^T  (no bias)
        gemm_kernel<<<dim3(M / 64, 1), 256, 0, stream>>>(
            buf_hn, HIDDEN, nullptr, 0, eW1l, 257, 0, nullptr, nullptr, buf_A, HIDDEN, 0);
        gemm_kernel<<<dim3(M / 64, 1), 256, 0, stream>>>(
            buf_hn, HIDDEN, nullptr, 0, eW1l, 257, 128, nullptr, nullptr, buf_B, HIDDEN, 0);

        // m_aggr (into buf_h; h is dead here)
        edge_kernel<<<dim3(M / 4), 256, 0, stream>>>(
            buf_A, buf_B, gc, colA, row_ptr, eW1l, eb1l, eW2l, eb2l, buf_h, M);

        // t = silu([hn | m_aggr] @ nW1^T + nb1)  (into buf_A; A is dead)
        gemm_kernel<<<dim3(M / 64, 1), 256, 0, stream>>>(
            buf_hn, HIDDEN, buf_h, HIDDEN, nW1l, 256, 0, nb1l, nullptr, buf_A, HIDDEN, 1);

        // h = hn + t @ nW2^T + nb2  (into buf_h; m_aggr dead)
        gemm_kernel<<<dim3(M / 64, 1), 256, 0, stream>>>(
            buf_A, HIDDEN, nullptr, 0, nW2l, HIDDEN, 0, nb2l, buf_hn, buf_h, HIDDEN, 0);
    }

    // out = h @ W_out^T + b_out   [M,128]x[128,1024]
    gemm_kernel<<<dim3(M / 64, CODE / 128), 256, 0, stream>>>(
        buf_h, HIDDEN, nullptr, 0, W_out, HIDDEN, 0, b_out, nullptr, out, CODE, 0);
}

// Round 2
// 1542.238 us; speedup vs baseline: 2.4376x; 2.4376x over previous
//
#include <hip/hip_runtime.h>
#include <math.h>

// GNN denoiser: N=32768 nodes, HID=128, L=4 layers.
// Edge MLP factorized: m1 = silu(A[u]+B[v]+dist*wd+eb1) built per 4-node tile
// into LDS (bf16, swizzled), then MFMA vs W2 (bf16, staged once per tile),
// silu epilogue + block-local segmented mean. No atomics.

#define HIDDEN 128
#define NLAYERS 4

typedef __attribute__((ext_vector_type(8))) short s16x8;
typedef __attribute__((ext_vector_type(4))) float f32x4;

__device__ __forceinline__ float silu_f(float x) {
    return x / (1.f + __expf(-x));
}
__device__ __forceinline__ unsigned short f2bf(float x) {
    unsigned int u = __float_as_uint(x);
    unsigned int r = u + 0x7fff + ((u >> 16) & 1);
    return (unsigned short)(r >> 16);
}
__device__ __forceinline__ float bf2f(unsigned short b) {
    return __uint_as_float(((unsigned int)b) << 16);
}

// row_ptr[v] = lower_bound(row, v), rows sorted ascending. v in [0, N].
__global__ __launch_bounds__(256) void rowptr_kernel(
    const int* __restrict__ row, int E, int N, int* __restrict__ rp) {
    int v = blockIdx.x * 256 + threadIdx.x;
    if (v > N) return;
    int lo = 0, hi = E;
    while (lo < hi) {
        int mid = (lo + hi) >> 1;
        if (row[mid] < v) lo = mid + 1; else hi = mid;
    }
    rp[v] = lo;
}

__global__ __launch_bounds__(256) void dist_kernel(
    const int* __restrict__ row, const int* __restrict__ col,
    const float* __restrict__ gc, float* __restrict__ dist, int E) {
    int t = blockIdx.x * 256 + threadIdx.x;
    if (t >= E) return;
    int u = col[t], v = row[t];
    float dx = gc[(size_t)u * 3 + 0] - gc[(size_t)v * 3 + 0];
    float dy = gc[(size_t)u * 3 + 1] - gc[(size_t)v * 3 + 1];
    float dz = gc[(size_t)u * 3 + 2] - gc[(size_t)v * 3 + 2];
    dist[t] = sqrtf(dx * dx + dy * dy + dz * dz);
}

// Per-layer prep: W2 -> bf16, wdeb[k] = (wd[k], eb1[k]). grid = NLAYERS.
__global__ __launch_bounds__(256) void prep_kernel(
    const float* __restrict__ eW1, const float* __restrict__ eb1,
    const float* __restrict__ eW2,
    unsigned short* __restrict__ w2bf, float2* __restrict__ wdeb) {
    int l = blockIdx.x;
    int tid = threadIdx.x;
    const float* eW2l = eW2 + (size_t)l * HIDDEN * HIDDEN;
    unsigned short* w2o = w2bf + (size_t)l * HIDDEN * HIDDEN;
    for (int i = tid; i < HIDDEN * HIDDEN; i += 256) w2o[i] = f2bf(eW2l[i]);
    if (tid < HIDDEN) {
        float2 p;
        p.x = eW1[(size_t)l * HIDDEN * 257 + (size_t)tid * 257 + 256];
        p.y = eb1[(size_t)l * HIDDEN + tid];
        wdeb[(size_t)l * HIDDEN + tid] = p;
    }
}

// LayerNorm over last dim (128). One wave per node, lane holds 2 elems.
__global__ __launch_bounds__(256) void ln_kernel(
    const float* __restrict__ h, const float* __restrict__ g,
    const float* __restrict__ b, float* __restrict__ hn, int N) {
    int tid = threadIdx.x;
    int wid = tid >> 6, l = tid & 63;
    int v = blockIdx.x * 4 + wid;
    if (v >= N) return;
    const float2* hp = reinterpret_cast<const float2*>(h + (size_t)v * HIDDEN);
    float2 x = hp[l];
    float sum = x.x + x.y;
#pragma unroll
    for (int o = 1; o < 64; o <<= 1) sum += __shfl_xor(sum, o, 64);
    float mu = sum * (1.f / 128.f);
    float d0 = x.x - mu, d1 = x.y - mu;
    float ssq = d0 * d0 + d1 * d1;
#pragma unroll
    for (int o = 1; o < 64; o <<= 1) ssq += __shfl_xor(ssq, o, 64);
    float rs = rsqrtf(ssq * (1.f / 128.f) + 1e-5f);
    float2 gg = reinterpret_cast<const float2*>(g)[l];
    float2 bb = reinterpret_cast<const float2*>(b)[l];
    float2 o2;
    o2.x = d0 * rs * gg.x + bb.x;
    o2.y = d1 * rs * gg.y + bb.y;
    reinterpret_cast<float2*>(hn + (size_t)v * HIDDEN)[l] = o2;
}

// Generic fp32 GEMM (unchanged from round 1).
__global__ __launch_bounds__(256) void gemm_kernel(
    const float* __restrict__ X1, int K1,
    const float* __restrict__ X2, int K2,
    const float* __restrict__ W, int ldW, int wOff,
    const float* __restrict__ bias,
    const float* __restrict__ resid,
    float* __restrict__ Y, int ldY,
    int act) {
    __shared__ float Xs[64 * 33];
    __shared__ float Ws[128 * 33];
    int tid = threadIdx.x;
    int tx = tid & 31, ty = tid >> 5;
    int row0 = blockIdx.x * 64;
    int cb = blockIdx.y * 128;
    int K = K1 + K2;
    float acc[8][4];
#pragma unroll
    for (int i = 0; i < 8; ++i)
#pragma unroll
        for (int j = 0; j < 4; ++j) acc[i][j] = 0.f;

    for (int kk0 = 0; kk0 < K; kk0 += 32) {
        const float* Xsrc;
        int ldX, koff;
        if (kk0 < K1) { Xsrc = X1; ldX = K1; koff = kk0; }
        else          { Xsrc = X2; ldX = K2; koff = kk0 - K1; }
        {
            int r = tid >> 3, kv = (tid & 7) * 4;
            const float4 a0 = *reinterpret_cast<const float4*>(
                Xsrc + (size_t)(row0 + r) * ldX + koff + kv);
            Xs[r * 33 + kv + 0] = a0.x; Xs[r * 33 + kv + 1] = a0.y;
            Xs[r * 33 + kv + 2] = a0.z; Xs[r * 33 + kv + 3] = a0.w;
            const float4 a1 = *reinterpret_cast<const float4*>(
                Xsrc + (size_t)(row0 + r + 32) * ldX + koff + kv);
            Xs[(r + 32) * 33 + kv + 0] = a1.x; Xs[(r + 32) * 33 + kv + 1] = a1.y;
            Xs[(r + 32) * 33 + kv + 2] = a1.z; Xs[(r + 32) * 33 + kv + 3] = a1.w;
        }
        {
            int kv = tid & 31, cbase = tid >> 5;
#pragma unroll
            for (int i = 0; i < 16; ++i) {
                int c = cbase + i * 8;
                Ws[c * 33 + kv] = W[(size_t)(cb + c) * ldW + wOff + kk0 + kv];
            }
        }
        __syncthreads();
#pragma unroll
        for (int kk = 0; kk < 32; ++kk) {
            float xv[8], wv[4];
#pragma unroll
            for (int i = 0; i < 8; ++i) xv[i] = Xs[(ty * 8 + i) * 33 + kk];
#pragma unroll
            for (int j = 0; j < 4; ++j) wv[j] = Ws[(tx + 32 * j) * 33 + kk];
#pragma unroll
            for (int i = 0; i < 8; ++i)
#pragma unroll
                for (int j = 0; j < 4; ++j) acc[i][j] += xv[i] * wv[j];
        }
        __syncthreads();
    }
#pragma unroll
    for (int i = 0; i < 8; ++i) {
        int row = row0 + ty * 8 + i;
#pragma unroll
        for (int j = 0; j < 4; ++j) {
            int c = tx + 32 * j;
            float val = acc[i][j];
            if (bias) val += bias[cb + c];
            if (resid) val += resid[(size_t)row * HIDDEN + c];
            if (act) val = silu_f(val);
            Y[(size_t)row * ldY + cb + c] = val;
        }
    }
}

// Edge MLP via MFMA. One block = 4 consecutive nodes (edges contiguous, <=72).
// LDS: m1 tile [80][128] bf16 (16B-chunk XOR swizzle), W2 [128][128] bf16
// (same swizzle), reused as mout after MFMA. Segmented mean -> mag (fp32).
__global__ __launch_bounds__(256) void edge_mfma_kernel(
    const float* __restrict__ A, const float* __restrict__ B,
    const int* __restrict__ rowv, const int* __restrict__ colv,
    const int* __restrict__ rp, const float* __restrict__ dist,
    const unsigned short* __restrict__ w2bf, const float2* __restrict__ wdeb,
    const float* __restrict__ eb2l, float* __restrict__ mag, int N) {
    __shared__ unsigned short m1[80 * 128];    // swizzled [r][k]; reused as mout [80][128]
    __shared__ unsigned short w2s[128 * 128];  // swizzled [n][k]
    __shared__ float2 wdebs[128];
    __shared__ int rpl[5];
    int tid = threadIdx.x;
    int v0 = blockIdx.x * 4;

    if (tid < 5) rpl[tid] = rp[v0 + tid];
    if (tid >= 32 && tid < 160) wdebs[tid - 32] = wdeb[tid - 32];
    // Stage W2 (swizzled): 2048 16B-chunks
    for (int j = tid; j < 2048; j += 256) {
        int n = j >> 4, c = j & 15;
        float4 w = *reinterpret_cast<const float4*>(w2bf + n * 128 + c * 8);
        *reinterpret_cast<float4*>(&w2s[n * 128 + ((c ^ (n & 7)) << 3)]) = w;
    }
    __syncthreads();

    int t0 = rpl[0];
    int nE = rpl[4] - t0;
    if (nE > 80) nE = 80;
    int nC = (nE + 15) >> 4;      // edge chunks of 16
    int R = nC << 4;

    // Construct m1 tile: task = (edge row r, 16B chunk c)
    for (int i = tid; i < R * 16; i += 256) {
        int r = i >> 4, c = i & 15;
        union { float4 f4; unsigned short us[8]; } pk;
        if (r < nE) {
            int t = t0 + r;
            int u = colv[t], vv = rowv[t];
            float d = dist[t];
            const float4* Ap = reinterpret_cast<const float4*>(A + (size_t)u * HIDDEN + c * 8);
            const float4* Bp = reinterpret_cast<const float4*>(B + (size_t)vv * HIDDEN + c * 8);
            float4 a0 = Ap[0], a1 = Ap[1];
            float4 b0 = Bp[0], b1 = Bp[1];
            float vals[8] = { a0.x + b0.x, a0.y + b0.y, a0.z + b0.z, a0.w + b0.w,
                              a1.x + b1.x, a1.y + b1.y, a1.z + b1.z, a1.w + b1.w };
#pragma unroll
            for (int j = 0; j < 8; ++j) {
                float2 we = wdebs[c * 8 + j];
                pk.us[j] = f2bf(silu_f(vals[j] + d * we.x + we.y));
            }
        } else {
            pk.f4 = make_float4(0.f, 0.f, 0.f, 0.f);
        }
        *reinterpret_cast<float4*>(&m1[r * 128 + ((c ^ (r & 7)) << 3)]) = pk.f4;
    }
    __syncthreads();

    // MFMA: wave wid owns n-range [wid*32, wid*32+32)
    int wid = tid >> 6, l = tid & 63;
    int lr = l & 15, lg = l >> 4;
    int nb = wid * 32;
    f32x4 acc[5][2];
#pragma unroll
    for (int mc = 0; mc < 5; ++mc)
#pragma unroll
        for (int f = 0; f < 2; ++f) {
            f32x4 z = { 0.f, 0.f, 0.f, 0.f };
            acc[mc][f] = z;
        }
#pragma unroll
    for (int ks = 0; ks < 4; ++ks) {
        int c = ks * 4 + lg;
        int n0 = nb + lr, n1 = n0 + 16;
        s16x8 bf0 = *reinterpret_cast<s16x8*>(&w2s[n0 * 128 + ((c ^ (n0 & 7)) << 3)]);
        s16x8 bf1 = *reinterpret_cast<s16x8*>(&w2s[n1 * 128 + ((c ^ (n1 & 7)) << 3)]);
#pragma unroll
        for (int mc = 0; mc < 5; ++mc) {
            if (mc < nC) {
                int r = mc * 16 + lr;
                s16x8 af = *reinterpret_cast<s16x8*>(&m1[r * 128 + ((c ^ (r & 7)) << 3)]);
                acc[mc][0] = __builtin_amdgcn_mfma_f32_16x16x32_bf16(af, bf0, acc[mc][0], 0, 0, 0);
                acc[mc][1] = __builtin_amdgcn_mfma_f32_16x16x32_bf16(af, bf1, acc[mc][1], 0, 0, 0);
            }
        }
    }
    __syncthreads();   // all frag reads of m1 done before overwrite

    // Epilogue: silu(acc + eb2) -> mout (reuse m1 space, plain [80][128] bf16)
    unsigned short* mout = m1;
#pragma unroll
    for (int f = 0; f < 2; ++f) {
        int n = nb + f * 16 + lr;
        float e2 = eb2l[n];
#pragma unroll
        for (int mc = 0; mc < 5; ++mc) {
            if (mc < nC) {
#pragma unroll
                for (int r4 = 0; r4 < 4; ++r4) {
                    int r = mc * 16 + lg * 4 + r4;
                    mout[r * 128 + n] = f2bf(silu_f(acc[mc][f][r4] + e2));
                }
            }
        }
    }
    __syncthreads();

    // Segmented mean per (node, channel)
    for (int i = tid; i < 512; i += 256) {
        int node = i >> 7, n = i & 127;
        int s = rpl[node] - t0, e = rpl[node + 1] - t0;
        if (e > 80) e = 80;
        float sum = 0.f;
        for (int r = s; r < e; ++r) sum += bf2f(mout[r * 128 + n]);
        float ic = (e > s) ? 1.f / (float)(e - s) : 0.f;
        mag[(size_t)(v0 + node) * HIDDEN + n] = sum * ic;
    }
}

extern "C" void kernel_launch(void* const* d_in, const int* in_sizes, int n_in,
                              void* d_out, int out_size, void* d_ws, size_t ws_size,
                              hipStream_t stream) {
    const float* y     = (const float*)d_in[0];
    const float* gc    = (const float*)d_in[1];
    const int*   eidx  = (const int*)d_in[2];
    const float* W_in  = (const float*)d_in[3];
    const float* b_in  = (const float*)d_in[4];
    const float* gam   = (const float*)d_in[5];
    const float* bet   = (const float*)d_in[6];
    const float* eW1   = (const float*)d_in[7];
    const float* eb1   = (const float*)d_in[8];
    const float* eW2   = (const float*)d_in[9];
    const float* eb2   = (const float*)d_in[10];
    const float* nW1   = (const float*)d_in[11];
    const float* nb1   = (const float*)d_in[12];
    const float* nW2   = (const float*)d_in[13];
    const float* nb2   = (const float*)d_in[14];
    const float* W_out = (const float*)d_in[15];
    const float* b_out = (const float*)d_in[16];

    const int CODE = in_sizes[16];          // 1024
    const int M = in_sizes[0] / CODE;       // 32768 nodes
    const int E = in_sizes[2] / 2;

    float* out = (float*)d_out;

    char* ws = (char*)d_ws;
    size_t off = 0;
    auto carve = [&](size_t bytes) {
        char* p = ws + off;
        off += (bytes + 255) & ~(size_t)255;
        return p;
    };
    float* buf_h  = (float*)carve((size_t)M * HIDDEN * 4);
    float* buf_hn = (float*)carve((size_t)M * HIDDEN * 4);
    float* buf_A  = (float*)carve((size_t)M * HIDDEN * 4);
    float* buf_B  = (float*)carve((size_t)M * HIDDEN * 4);
    int*   row_ptr = (int*)carve((size_t)(M + 1) * 4);
    float* dist   = (float*)carve((size_t)E * 4);
    unsigned short* w2bf = (unsigned short*)carve((size_t)NLAYERS * HIDDEN * HIDDEN * 2);
    float2* wdeb  = (float2*)carve((size_t)NLAYERS * HIDDEN * 8);

    const int* row  = eidx;
    const int* colA = eidx + E;

    rowptr_kernel<<<dim3((M + 1 + 255) / 256), 256, 0, stream>>>(row, E, M, row_ptr);
    dist_kernel<<<dim3((E + 255) / 256), 256, 0, stream>>>(row, colA, gc, dist, E);
    prep_kernel<<<dim3(NLAYERS), 256, 0, stream>>>(eW1, eb1, eW2, w2bf, wdeb);

    // h = y @ W_in^T + b_in
    gemm_kernel<<<dim3(M / 64, 1), 256, 0, stream>>>(
        y, CODE, nullptr, 0, W_in, CODE, 0, b_in, nullptr, buf_h, HIDDEN, 0);

    for (int l = 0; l < NLAYERS; ++l) {
        const float* eW1l = eW1 + (size_t)l * HIDDEN * 257;
        const float* eb2l = eb2 + (size_t)l * HIDDEN;
        const float* nW1l = nW1 + (size_t)l * HIDDEN * 256;
        const float* nb1l = nb1 + (size_t)l * HIDDEN;
        const float* nW2l = nW2 + (size_t)l * HIDDEN * HIDDEN;
        const float* nb2l = nb2 + (size_t)l * HIDDEN;

        ln_kernel<<<dim3(M / 4), 256, 0, stream>>>(
            buf_h, gam + (size_t)l * HIDDEN, bet + (size_t)l * HIDDEN, buf_hn, M);

        gemm_kernel<<<dim3(M / 64, 1), 256, 0, stream>>>(
            buf_hn, HIDDEN, nullptr, 0, eW1l, 257, 0, nullptr, nullptr, buf_A, HIDDEN, 0);
        gemm_kernel<<<dim3(M / 64, 1), 256, 0, stream>>>(
            buf_hn, HIDDEN, nullptr, 0, eW1l, 257, 128, nullptr, nullptr, buf_B, HIDDEN, 0);

        // m_aggr into buf_h (h dead after LN)
        edge_mfma_kernel<<<dim3(M / 4), 256, 0, stream>>>(
            buf_A, buf_B, row, colA, row_ptr, dist,
            w2bf + (size_t)l * HIDDEN * HIDDEN, wdeb + (size_t)l * HIDDEN,
            eb2l, buf_h, M);

        gemm_kernel<<<dim3(M / 64, 1), 256, 0, stream>>>(
            buf_hn, HIDDEN, buf_h, HIDDEN, nW1l, 256, 0, nb1l, nullptr, buf_A, HIDDEN, 1);

        gemm_kernel<<<dim3(M / 64, 1), 256, 0, stream>>>(
            buf_A, HIDDEN, nullptr, 0, nW2l, HIDDEN, 0, nb2l, buf_hn, buf_h, HIDDEN, 0);
    }

    gemm_kernel<<<dim3(M / 64, CODE / 128), 256, 0, stream>>>(
        buf_h, HIDDEN, nullptr, 0, W_out, HIDDEN, 0, b_out, nullptr, out, CODE, 0);
}

// Round 3
// 985.667 us; speedup vs baseline: 3.8141x; 1.5647x over previous
//
#include <hip/hip_runtime.h>
#include <math.h>

// GNN denoiser: N=32768 nodes, HID=128, L=4 layers. All GEMMs via bf16 MFMA
// (fp32 accumulate, fp32 residual stream). Edge MLP: W2 frags in registers,
// m1 built bf16-swizzled in LDS, segmented mean computed from MFMA accums
// in-register (no atomics, no LDS round-trip).

#define HIDDEN 128
#define NLAYERS 4

typedef __attribute__((ext_vector_type(8))) short s16x8;
typedef __attribute__((ext_vector_type(4))) float f32x4;

__device__ __forceinline__ float silu_f(float x) {
    return x / (1.f + __expf(-x));
}
__device__ __forceinline__ unsigned short f2bf(float x) {
    unsigned int u = __float_as_uint(x);
    unsigned int r = u + 0x7fff + ((u >> 16) & 1);
    return (unsigned short)(r >> 16);
}
__device__ __forceinline__ float bf2f(unsigned short b) {
    return __uint_as_float(((unsigned int)b) << 16);
}

// ---------------- graph prep ----------------
__global__ __launch_bounds__(256) void rowptr_kernel(
    const int* __restrict__ row, int E, int N, int* __restrict__ rp) {
    int v = blockIdx.x * 256 + threadIdx.x;
    if (v > N) return;
    int lo = 0, hi = E;
    while (lo < hi) {
        int mid = (lo + hi) >> 1;
        if (row[mid] < v) lo = mid + 1; else hi = mid;
    }
    rp[v] = lo;
}

__global__ __launch_bounds__(256) void dist_kernel(
    const int* __restrict__ row, const int* __restrict__ col,
    const float* __restrict__ gc, float* __restrict__ dist, int E) {
    int t = blockIdx.x * 256 + threadIdx.x;
    if (t >= E) return;
    int u = col[t], v = row[t];
    float dx = gc[(size_t)u * 3 + 0] - gc[(size_t)v * 3 + 0];
    float dy = gc[(size_t)u * 3 + 1] - gc[(size_t)v * 3 + 1];
    float dz = gc[(size_t)u * 3 + 2] - gc[(size_t)v * 3 + 2];
    dist[t] = sqrtf(dx * dx + dy * dy + dz * dz);
}

// ---------------- weight prep ----------------
__global__ __launch_bounds__(256) void conv_kernel(
    const float* __restrict__ s, unsigned short* __restrict__ d, int n) {
    int i = (blockIdx.x * 256 + threadIdx.x) * 4;
    if (i >= n) return;
    float4 v = *reinterpret_cast<const float4*>(s + i);
    ushort4 o;
    o.x = f2bf(v.x); o.y = f2bf(v.y); o.z = f2bf(v.z); o.w = f2bf(v.w);
    *reinterpret_cast<ushort4*>(d + i) = o;
}

// Pack per-layer: w1ab [256][128] bf16 (A rows then B rows), bias256, wd.
__global__ __launch_bounds__(256) void pack_kernel(
    const float* __restrict__ eW1, const float* __restrict__ eb1,
    unsigned short* __restrict__ w1ab, float* __restrict__ bias256,
    float* __restrict__ wdl) {
    int l = blockIdx.x;
    int tid = threadIdx.x;
    const float* w = eW1 + (size_t)l * HIDDEN * 257;
    for (int i = tid; i < 256 * 128; i += 256) {
        int n = i >> 7, k = i & 127;
        float v = (n < 128) ? w[(size_t)n * 257 + k]
                            : w[(size_t)(n - 128) * 257 + 128 + k];
        w1ab[(size_t)l * 256 * 128 + i] = f2bf(v);
    }
    if (tid < 256)
        bias256[(size_t)l * 256 + tid] =
            (tid < 128) ? 0.f : eb1[(size_t)l * HIDDEN + tid - 128];
    if (tid < 128)
        wdl[(size_t)l * HIDDEN + tid] = w[(size_t)tid * 257 + 256];
}

// ---------------- LayerNorm (fp32 in, fp32 + bf16 out) ----------------
__global__ __launch_bounds__(256) void ln_kernel(
    const float* __restrict__ h, const float* __restrict__ g,
    const float* __restrict__ b, float* __restrict__ hn,
    unsigned short* __restrict__ hnbf, int N) {
    int tid = threadIdx.x;
    int wid = tid >> 6, l = tid & 63;
    int v = blockIdx.x * 4 + wid;
    if (v >= N) return;
    const float2* hp = reinterpret_cast<const float2*>(h + (size_t)v * HIDDEN);
    float2 x = hp[l];
    float sum = x.x + x.y;
#pragma unroll
    for (int o = 1; o < 64; o <<= 1) sum += __shfl_xor(sum, o, 64);
    float mu = sum * (1.f / 128.f);
    float d0 = x.x - mu, d1 = x.y - mu;
    float ssq = d0 * d0 + d1 * d1;
#pragma unroll
    for (int o = 1; o < 64; o <<= 1) ssq += __shfl_xor(ssq, o, 64);
    float rs = rsqrtf(ssq * (1.f / 128.f) + 1e-5f);
    float2 gg = reinterpret_cast<const float2*>(g)[l];
    float2 bb = reinterpret_cast<const float2*>(b)[l];
    float2 o2;
    o2.x = d0 * rs * gg.x + bb.x;
    o2.y = d1 * rs * gg.y + bb.y;
    reinterpret_cast<float2*>(hn + (size_t)v * HIDDEN)[l] = o2;
    ushort2 ob;
    ob.x = f2bf(o2.x); ob.y = f2bf(o2.y);
    *reinterpret_cast<ushort2*>(hnbf + (size_t)v * HIDDEN + 2 * l) = ob;
}

// ---------------- bf16 MFMA GEMM ----------------
// C[row0..+128, cb..+128] = act( [A1|A2] @ W^T + bias + resid )
// A1: [M,K1] bf16 (or A1f fp32), A2: [M,K2] bf16, W: [Ntot][K] bf16 row-major.
__global__ __launch_bounds__(256) void mgemm(
    const unsigned short* __restrict__ A1, const float* __restrict__ A1f, int K1,
    const unsigned short* __restrict__ A2, int K2,
    const unsigned short* __restrict__ W,
    const float* __restrict__ bias, const float* __restrict__ resid,
    float* __restrict__ Cf, unsigned short* __restrict__ Cb, int ldC, int act) {
    __shared__ unsigned short As[128 * 128];
    __shared__ unsigned short Ws[128 * 128];
    int tid = threadIdx.x;
    int wid = tid >> 6, l = tid & 63, lr = l & 15, lg = l >> 4;
    int wm = wid >> 1, wn = wid & 1;
    int row0 = blockIdx.x * 128;
    int cb = blockIdx.y * 128;
    int K = K1 + K2;
    f32x4 acc[4][4];
#pragma unroll
    for (int i = 0; i < 4; ++i)
#pragma unroll
        for (int j = 0; j < 4; ++j) {
            f32x4 z = { 0.f, 0.f, 0.f, 0.f };
            acc[i][j] = z;
        }

    for (int kc = 0; kc < K; kc += 128) {
#pragma unroll
        for (int jj = 0; jj < 8; ++jj) {
            int j = tid + jj * 256;           // 2048 chunk tasks
            int r = j >> 4, c = j & 15;
            int gk = kc + c * 8;
            s16x8 v;
            if (gk < K1) {
                if (A1f) {
                    const float* p = A1f + (size_t)(row0 + r) * K1 + gk;
                    float4 f0 = *reinterpret_cast<const float4*>(p);
                    float4 f1 = *reinterpret_cast<const float4*>(p + 4);
                    union { s16x8 s; unsigned short u[8]; } pk;
                    pk.u[0] = f2bf(f0.x); pk.u[1] = f2bf(f0.y);
                    pk.u[2] = f2bf(f0.z); pk.u[3] = f2bf(f0.w);
                    pk.u[4] = f2bf(f1.x); pk.u[5] = f2bf(f1.y);
                    pk.u[6] = f2bf(f1.z); pk.u[7] = f2bf(f1.w);
                    v = pk.s;
                } else {
                    v = *reinterpret_cast<const s16x8*>(
                        A1 + (size_t)(row0 + r) * K1 + gk);
                }
            } else {
                v = *reinterpret_cast<const s16x8*>(
                    A2 + (size_t)(row0 + r) * K2 + (gk - K1));
            }
            *reinterpret_cast<s16x8*>(&As[r * 128 + ((c ^ (r & 7)) << 3)]) = v;
            s16x8 wv = *reinterpret_cast<const s16x8*>(
                W + (size_t)(cb + r) * K + kc + c * 8);
            *reinterpret_cast<s16x8*>(&Ws[r * 128 + ((c ^ (r & 7)) << 3)]) = wv;
        }
        __syncthreads();
#pragma unroll
        for (int ks = 0; ks < 4; ++ks) {
            int c = ks * 4 + lg;
            s16x8 af[4], bf[4];
#pragma unroll
            for (int i = 0; i < 4; ++i) {
                int r = wm * 64 + i * 16 + lr;
                af[i] = *reinterpret_cast<s16x8*>(&As[r * 128 + ((c ^ (r & 7)) << 3)]);
                int n = wn * 64 + i * 16 + lr;
                bf[i] = *reinterpret_cast<s16x8*>(&Ws[n * 128 + ((c ^ (n & 7)) << 3)]);
            }
#pragma unroll
            for (int mi = 0; mi < 4; ++mi)
#pragma unroll
                for (int ni = 0; ni < 4; ++ni)
                    acc[mi][ni] = __builtin_amdgcn_mfma_f32_16x16x32_bf16(
                        af[mi], bf[ni], acc[mi][ni], 0, 0, 0);
        }
        __syncthreads();
    }
#pragma unroll
    for (int mi = 0; mi < 4; ++mi) {
#pragma unroll
        for (int ni = 0; ni < 4; ++ni) {
            int colg = cb + wn * 64 + ni * 16 + lr;
            float bs = bias ? bias[colg] : 0.f;
#pragma unroll
            for (int r4 = 0; r4 < 4; ++r4) {
                int rowg = row0 + wm * 64 + mi * 16 + lg * 4 + r4;
                float v = acc[mi][ni][r4] + bs;
                if (resid) v += resid[(size_t)rowg * HIDDEN + colg];
                if (act) v = silu_f(v);
                if (Cf) Cf[(size_t)rowg * ldC + colg] = v;
                if (Cb) Cb[(size_t)rowg * ldC + colg] = f2bf(v);
            }
        }
    }
}

// ---------------- edge MLP + in-register segmented mean ----------------
// Block = 4 consecutive dest nodes (<=72 contiguous edges).
__global__ __launch_bounds__(256) void edge_mfma2(
    const unsigned short* __restrict__ ABbf,
    const int* __restrict__ rowv, const int* __restrict__ colv,
    const int* __restrict__ rp, const float* __restrict__ dist,
    const unsigned short* __restrict__ w2bf, const float* __restrict__ wdl,
    const float* __restrict__ eb2l, unsigned short* __restrict__ magbf, int N) {
    __shared__ unsigned short m1[72 * 128];   // XOR-swizzled [r][k]
    __shared__ float wds[128];
    __shared__ int rpl[5];
    int tid = threadIdx.x;
    int v0 = blockIdx.x * 4;
    if (tid < 5) rpl[tid] = rp[v0 + tid];
    if (tid >= 64 && tid < 192) wds[tid - 64] = wdl[tid - 64];

    int wid = tid >> 6, l = tid & 63, lr = l & 15, lg = l >> 4;
    int nb = wid * 32;
    // W2 B-frags straight to registers (layer W2 is L2-resident)
    s16x8 wfr[4][2];
#pragma unroll
    for (int ks = 0; ks < 4; ++ks)
#pragma unroll
        for (int ni = 0; ni < 2; ++ni) {
            int n = nb + ni * 16 + lr;
            wfr[ks][ni] = *reinterpret_cast<const s16x8*>(
                w2bf + (size_t)n * 128 + (ks * 4 + lg) * 8);
        }
    __syncthreads();

    int t0 = rpl[0];
    int nE = rpl[4] - t0;
    if (nE > 72) nE = 72;
    int nC = (nE + 15) >> 4;

    // Build m1 = silu(A[u] + (B[v]+eb1) + d*wd) as bf16, swizzled.
    for (int i = tid; i < nE * 16; i += 256) {
        int r = i >> 4, c = i & 15;
        int t = t0 + r;
        int u = colv[t], vv = rowv[t];
        float d = dist[t];
        union { s16x8 s; unsigned short u[8]; } av, bv, pk;
        av.s = *reinterpret_cast<const s16x8*>(ABbf + (size_t)u * 256 + c * 8);
        bv.s = *reinterpret_cast<const s16x8*>(ABbf + (size_t)vv * 256 + 128 + c * 8);
#pragma unroll
        for (int j = 0; j < 8; ++j) {
            float val = bf2f(av.u[j]) + bf2f(bv.u[j]) + d * wds[c * 8 + j];
            pk.u[j] = f2bf(silu_f(val));
        }
        *reinterpret_cast<s16x8*>(&m1[r * 128 + ((c ^ (r & 7)) << 3)]) = pk.s;
    }
    __syncthreads();

    f32x4 acc[5][2];
#pragma unroll
    for (int mc = 0; mc < 5; ++mc)
#pragma unroll
        for (int f = 0; f < 2; ++f) {
            f32x4 z = { 0.f, 0.f, 0.f, 0.f };
            acc[mc][f] = z;
        }
#pragma unroll
    for (int ks = 0; ks < 4; ++ks) {
        int c = ks * 4 + lg;
#pragma unroll
        for (int mc = 0; mc < 5; ++mc) {
            if (mc < nC) {
                int r = mc * 16 + lr;
                int rc = (r < nE) ? r : 0;
                s16x8 af = *reinterpret_cast<s16x8*>(
                    &m1[rc * 128 + ((c ^ (rc & 7)) << 3)]);
                acc[mc][0] = __builtin_amdgcn_mfma_f32_16x16x32_bf16(
                    af, wfr[ks][0], acc[mc][0], 0, 0, 0);
                acc[mc][1] = __builtin_amdgcn_mfma_f32_16x16x32_bf16(
                    af, wfr[ks][1], acc[mc][1], 0, 0, 0);
            }
        }
    }

    // silu(acc + eb2) and segmented mean, fully in-register.
    int o1 = rpl[1] - t0, o2 = rpl[2] - t0, o3 = rpl[3] - t0;
    float e20 = eb2l[nb + lr], e21 = eb2l[nb + 16 + lr];
    float mac[2][4];
#pragma unroll
    for (int f = 0; f < 2; ++f)
#pragma unroll
        for (int nd = 0; nd < 4; ++nd) mac[f][nd] = 0.f;
#pragma unroll
    for (int mc = 0; mc < 5; ++mc) {
        if (mc < nC) {
#pragma unroll
            for (int r4 = 0; r4 < 4; ++r4) {
                int r = mc * 16 + lg * 4 + r4;
                bool vd = r < nE;
                bool s0 = vd & (r < o1);
                bool s1 = vd & (r >= o1) & (r < o2);
                bool s2 = vd & (r >= o2) & (r < o3);
                bool s3 = vd & (r >= o3);
                float sv0 = silu_f(acc[mc][0][r4] + e20);
                float sv1 = silu_f(acc[mc][1][r4] + e21);
                mac[0][0] += s0 ? sv0 : 0.f;
                mac[0][1] += s1 ? sv0 : 0.f;
                mac[0][2] += s2 ? sv0 : 0.f;
                mac[0][3] += s3 ? sv0 : 0.f;
                mac[1][0] += s0 ? sv1 : 0.f;
                mac[1][1] += s1 ? sv1 : 0.f;
                mac[1][2] += s2 ? sv1 : 0.f;
                mac[1][3] += s3 ? sv1 : 0.f;
            }
        }
    }
#pragma unroll
    for (int f = 0; f < 2; ++f)
#pragma unroll
        for (int nd = 0; nd < 4; ++nd) {
            float x = mac[f][nd];
            x += __shfl_xor(x, 16, 64);
            x += __shfl_xor(x, 32, 64);
            mac[f][nd] = x;
        }
    float c0 = (float)(rpl[1] - rpl[0]);
    float c1 = (float)(rpl[2] - rpl[1]);
    float c2 = (float)(rpl[3] - rpl[2]);
    float c3 = (float)(rpl[4] - rpl[3]);
    float iv0 = c0 > 0.f ? 1.f / c0 : 0.f;
    float iv1 = c1 > 0.f ? 1.f / c1 : 0.f;
    float iv2 = c2 > 0.f ? 1.f / c2 : 0.f;
    float iv3 = c3 > 0.f ? 1.f / c3 : 0.f;
    float sel0 = (lg == 0) ? mac[0][0] : (lg == 1) ? mac[0][1]
               : (lg == 2) ? mac[0][2] : mac[0][3];
    float sel1 = (lg == 0) ? mac[1][0] : (lg == 1) ? mac[1][1]
               : (lg == 2) ? mac[1][2] : mac[1][3];
    float ivn  = (lg == 0) ? iv0 : (lg == 1) ? iv1 : (lg == 2) ? iv2 : iv3;
    magbf[(size_t)(v0 + lg) * HIDDEN + nb + lr] = f2bf(sel0 * ivn);
    magbf[(size_t)(v0 + lg) * HIDDEN + nb + 16 + lr] = f2bf(sel1 * ivn);
}

extern "C" void kernel_launch(void* const* d_in, const int* in_sizes, int n_in,
                              void* d_out, int out_size, void* d_ws, size_t ws_size,
                              hipStream_t stream) {
    const float* y     = (const float*)d_in[0];
    const float* gc    = (const float*)d_in[1];
    const int*   eidx  = (const int*)d_in[2];
    const float* W_in  = (const float*)d_in[3];
    const float* b_in  = (const float*)d_in[4];
    const float* gam   = (const float*)d_in[5];
    const float* bet   = (const float*)d_in[6];
    const float* eW1   = (const float*)d_in[7];
    const float* eb1   = (const float*)d_in[8];
    const float* eW2   = (const float*)d_in[9];
    const float* eb2   = (const float*)d_in[10];
    const float* nW1   = (const float*)d_in[11];
    const float* nb1   = (const float*)d_in[12];
    const float* nW2   = (const float*)d_in[13];
    const float* nb2   = (const float*)d_in[14];
    const float* W_out = (const float*)d_in[15];
    const float* b_out = (const float*)d_in[16];

    const int CODE = in_sizes[16];          // 1024
    const int M = in_sizes[0] / CODE;       // 32768 nodes
    const int E = in_sizes[2] / 2;

    float* out = (float*)d_out;

    char* ws = (char*)d_ws;
    size_t off = 0;
    auto carve = [&](size_t bytes) {
        char* p = ws + off;
        off += (bytes + 255) & ~(size_t)255;
        return p;
    };
    float*          buf_h   = (float*)carve((size_t)M * HIDDEN * 4);
    float*          buf_hn  = (float*)carve((size_t)M * HIDDEN * 4);
    unsigned short* hnbf    = (unsigned short*)carve((size_t)M * HIDDEN * 2);
    unsigned short* ABbf    = (unsigned short*)carve((size_t)M * 256 * 2);
    unsigned short* magbf   = (unsigned short*)carve((size_t)M * HIDDEN * 2);
    unsigned short* hbf     = (unsigned short*)carve((size_t)M * HIDDEN * 2);
    int*            row_ptr = (int*)carve((size_t)(M + 1) * 4);
    float*          dist    = (float*)carve((size_t)E * 4);
    unsigned short* winbf   = (unsigned short*)carve((size_t)HIDDEN * CODE * 2);
    unsigned short* woutbf  = (unsigned short*)carve((size_t)CODE * HIDDEN * 2);
    unsigned short* wn1bf   = (unsigned short*)carve((size_t)NLAYERS * HIDDEN * 256 * 2);
    unsigned short* wn2bf   = (unsigned short*)carve((size_t)NLAYERS * HIDDEN * HIDDEN * 2);
    unsigned short* w2bf    = (unsigned short*)carve((size_t)NLAYERS * HIDDEN * HIDDEN * 2);
    unsigned short* w1ab    = (unsigned short*)carve((size_t)NLAYERS * 256 * HIDDEN * 2);
    float*          bias256 = (float*)carve((size_t)NLAYERS * 256 * 4);
    float*          wdl     = (float*)carve((size_t)NLAYERS * HIDDEN * 4);
    unsigned short* tbf     = (unsigned short*)ABbf;   // overlay: AB dead by nMLP1

    const int* row  = eidx;
    const int* colA = eidx + E;

    rowptr_kernel<<<dim3((M + 1 + 255) / 256), 256, 0, stream>>>(row, E, M, row_ptr);
    dist_kernel<<<dim3((E + 255) / 256), 256, 0, stream>>>(row, colA, gc, dist, E);

    conv_kernel<<<dim3(HIDDEN * CODE / 1024), 256, 0, stream>>>(W_in, winbf, HIDDEN * CODE);
    conv_kernel<<<dim3(CODE * HIDDEN / 1024), 256, 0, stream>>>(W_out, woutbf, CODE * HIDDEN);
    conv_kernel<<<dim3(NLAYERS * HIDDEN * 256 / 1024), 256, 0, stream>>>(
        nW1, wn1bf, NLAYERS * HIDDEN * 256);
    conv_kernel<<<dim3(NLAYERS * HIDDEN * HIDDEN / 1024), 256, 0, stream>>>(
        nW2, wn2bf, NLAYERS * HIDDEN * HIDDEN);
    conv_kernel<<<dim3(NLAYERS * HIDDEN * HIDDEN / 1024), 256, 0, stream>>>(
        eW2, w2bf, NLAYERS * HIDDEN * HIDDEN);
    pack_kernel<<<dim3(NLAYERS), 256, 0, stream>>>(eW1, eb1, w1ab, bias256, wdl);

    // h = y @ W_in^T + b_in (fp32 A converted in staging)
    mgemm<<<dim3(M / 128, 1), 256, 0, stream>>>(
        nullptr, y, CODE, nullptr, 0, winbf, b_in, nullptr, buf_h, nullptr, HIDDEN, 0);

    for (int l = 0; l < NLAYERS; ++l) {
        const float* eb2l = eb2 + (size_t)l * HIDDEN;
        const float* nb1l = nb1 + (size_t)l * HIDDEN;
        const float* nb2l = nb2 + (size_t)l * HIDDEN;

        ln_kernel<<<dim3(M / 4), 256, 0, stream>>>(
            buf_h, gam + (size_t)l * HIDDEN, bet + (size_t)l * HIDDEN,
            buf_hn, hnbf, M);

        // [A|B] = hn @ w1ab^T + bias256 (B part has +eb1), bf16 out
        mgemm<<<dim3(M / 128, 2), 256, 0, stream>>>(
            hnbf, nullptr, HIDDEN, nullptr, 0,
            w1ab + (size_t)l * 256 * HIDDEN, bias256 + (size_t)l * 256,
            nullptr, nullptr, ABbf, 256, 0);

        edge_mfma2<<<dim3(M / 4), 256, 0, stream>>>(
            ABbf, row, colA, row_ptr, dist,
            w2bf + (size_t)l * HIDDEN * HIDDEN, wdl + (size_t)l * HIDDEN,
            eb2l, magbf, M);

        // t = silu([hn | m_aggr] @ nW1^T + nb1), bf16 out (overlays AB)
        mgemm<<<dim3(M / 128, 1), 256, 0, stream>>>(
            hnbf, nullptr, HIDDEN, magbf, HIDDEN,
            wn1bf + (size_t)l * HIDDEN * 256, nb1l,
            nullptr, nullptr, tbf, HIDDEN, 1);

        // h = hn + t @ nW2^T + nb2 (fp32; also bf16 on last layer)
        mgemm<<<dim3(M / 128, 1), 256, 0, stream>>>(
            tbf, nullptr, HIDDEN, nullptr, 0,
            wn2bf + (size_t)l * HIDDEN * HIDDEN, nb2l,
            buf_hn, buf_h, (l == NLAYERS - 1) ? hbf : nullptr, HIDDEN, 0);
    }

    // out = h @ W_out^T + b_out
    mgemm<<<dim3(M / 128, CODE / 128), 256, 0, stream>>>(
        hbf, nullptr, HIDDEN, nullptr, 0, woutbf, b_out,
        nullptr, out, nullptr, CODE, 0);
}

// Round 4
// 771.104 us; speedup vs baseline: 4.8754x; 1.2783x over previous
//
#include <hip/hip_runtime.h>
#include <math.h>

// GNN denoiser: N=32768 nodes, HID=128, L=4 layers. All GEMMs via bf16 MFMA
// (fp32 accumulate, fp32 residual stream). Edge MLP: W2 frags in registers,
// m1 built bf16-swizzled in LDS (fast silu + v_cvt_pk_bf16), segmented mean
// in-register. Node MLP (n1+n2) fused into one two-stage MFMA kernel.

#define HIDDEN 128
#define NLAYERS 4

typedef __attribute__((ext_vector_type(8))) short s16x8;
typedef __attribute__((ext_vector_type(4))) float f32x4;

__device__ __forceinline__ unsigned int cvt_pk_bf16(float lo, float hi) {
    unsigned int d;
    asm("v_cvt_pk_bf16_f32 %0, %1, %2" : "=v"(d) : "v"(lo), "v"(hi));
    return d;
}
__device__ __forceinline__ unsigned short f2bf(float x) {
    return (unsigned short)cvt_pk_bf16(x, x);
}
__device__ __forceinline__ float silu_f(float x) {
    float e = __expf(-x);
    float r;
    asm("v_rcp_f32 %0, %1" : "=v"(r) : "v"(1.f + e));
    return x * r;
}
__device__ __forceinline__ float bf2f(unsigned short b) {
    return __uint_as_float(((unsigned int)b) << 16);
}

// ---------------- graph prep ----------------
__global__ __launch_bounds__(256) void rowptr_kernel(
    const int* __restrict__ row, int E, int N, int* __restrict__ rp) {
    int v = blockIdx.x * 256 + threadIdx.x;
    if (v > N) return;
    int lo = 0, hi = E;
    while (lo < hi) {
        int mid = (lo + hi) >> 1;
        if (row[mid] < v) lo = mid + 1; else hi = mid;
    }
    rp[v] = lo;
}

__global__ __launch_bounds__(256) void dist_kernel(
    const int* __restrict__ row, const int* __restrict__ col,
    const float* __restrict__ gc, float* __restrict__ dist, int E) {
    int t = blockIdx.x * 256 + threadIdx.x;
    if (t >= E) return;
    int u = col[t], v = row[t];
    float dx = gc[(size_t)u * 3 + 0] - gc[(size_t)v * 3 + 0];
    float dy = gc[(size_t)u * 3 + 1] - gc[(size_t)v * 3 + 1];
    float dz = gc[(size_t)u * 3 + 2] - gc[(size_t)v * 3 + 2];
    dist[t] = sqrtf(dx * dx + dy * dy + dz * dz);
}

// ---------------- weight prep ----------------
__global__ __launch_bounds__(256) void conv_kernel(
    const float* __restrict__ s, unsigned short* __restrict__ d, int n) {
    int i = (blockIdx.x * 256 + threadIdx.x) * 4;
    if (i >= n) return;
    float4 v = *reinterpret_cast<const float4*>(s + i);
    unsigned int lo = cvt_pk_bf16(v.x, v.y);
    unsigned int hi = cvt_pk_bf16(v.z, v.w);
    uint2 o = { lo, hi };
    *reinterpret_cast<uint2*>(d + i) = o;
}

// Pack per-layer: w1ab [256][128] bf16 (A rows then B rows), bias256, wd.
__global__ __launch_bounds__(256) void pack_kernel(
    const float* __restrict__ eW1, const float* __restrict__ eb1,
    unsigned short* __restrict__ w1ab, float* __restrict__ bias256,
    float* __restrict__ wdl) {
    int l = blockIdx.x;
    int tid = threadIdx.x;
    const float* w = eW1 + (size_t)l * HIDDEN * 257;
    for (int i = tid; i < 256 * 128; i += 256) {
        int n = i >> 7, k = i & 127;
        float v = (n < 128) ? w[(size_t)n * 257 + k]
                            : w[(size_t)(n - 128) * 257 + 128 + k];
        w1ab[(size_t)l * 256 * 128 + i] = f2bf(v);
    }
    if (tid < 256)
        bias256[(size_t)l * 256 + tid] =
            (tid < 128) ? 0.f : eb1[(size_t)l * HIDDEN + tid - 128];
    if (tid < 128)
        wdl[(size_t)l * HIDDEN + tid] = w[(size_t)tid * 257 + 256];
}

// ---------------- LayerNorm (fp32 in, fp32 + bf16 out) ----------------
__global__ __launch_bounds__(256) void ln_kernel(
    const float* __restrict__ h, const float* __restrict__ g,
    const float* __restrict__ b, float* __restrict__ hn,
    unsigned short* __restrict__ hnbf, int N) {
    int tid = threadIdx.x;
    int wid = tid >> 6, l = tid & 63;
    int v = blockIdx.x * 4 + wid;
    if (v >= N) return;
    const float2* hp = reinterpret_cast<const float2*>(h + (size_t)v * HIDDEN);
    float2 x = hp[l];
    float sum = x.x + x.y;
#pragma unroll
    for (int o = 1; o < 64; o <<= 1) sum += __shfl_xor(sum, o, 64);
    float mu = sum * (1.f / 128.f);
    float d0 = x.x - mu, d1 = x.y - mu;
    float ssq = d0 * d0 + d1 * d1;
#pragma unroll
    for (int o = 1; o < 64; o <<= 1) ssq += __shfl_xor(ssq, o, 64);
    float rs = rsqrtf(ssq * (1.f / 128.f) + 1e-5f);
    float2 gg = reinterpret_cast<const float2*>(g)[l];
    float2 bb = reinterpret_cast<const float2*>(b)[l];
    float2 o2;
    o2.x = d0 * rs * gg.x + bb.x;
    o2.y = d1 * rs * gg.y + bb.y;
    reinterpret_cast<float2*>(hn + (size_t)v * HIDDEN)[l] = o2;
    *reinterpret_cast<unsigned int*>(hnbf + (size_t)v * HIDDEN + 2 * l) =
        cvt_pk_bf16(o2.x, o2.y);
}

// ---------------- bf16 MFMA GEMM ----------------
__global__ __launch_bounds__(256) void mgemm(
    const unsigned short* __restrict__ A1, const float* __restrict__ A1f, int K1,
    const unsigned short* __restrict__ A2, int K2,
    const unsigned short* __restrict__ W,
    const float* __restrict__ bias, const float* __restrict__ resid,
    float* __restrict__ Cf, unsigned short* __restrict__ Cb, int ldC, int act) {
    __shared__ __align__(16) unsigned short As[128 * 128];
    __shared__ __align__(16) unsigned short Ws[128 * 128];
    int tid = threadIdx.x;
    int wid = tid >> 6, l = tid & 63, lr = l & 15, lg = l >> 4;
    int wm = wid >> 1, wn = wid & 1;
    int row0 = blockIdx.x * 128;
    int cb = blockIdx.y * 128;
    int K = K1 + K2;
    f32x4 acc[4][4];
#pragma unroll
    for (int i = 0; i < 4; ++i)
#pragma unroll
        for (int j = 0; j < 4; ++j) {
            f32x4 z = { 0.f, 0.f, 0.f, 0.f };
            acc[i][j] = z;
        }

    for (int kc = 0; kc < K; kc += 128) {
#pragma unroll
        for (int jj = 0; jj < 8; ++jj) {
            int j = tid + jj * 256;
            int r = j >> 4, c = j & 15;
            int gk = kc + c * 8;
            s16x8 v;
            if (gk < K1) {
                if (A1f) {
                    const float* p = A1f + (size_t)(row0 + r) * K1 + gk;
                    float4 f0 = *reinterpret_cast<const float4*>(p);
                    float4 f1 = *reinterpret_cast<const float4*>(p + 4);
                    union { s16x8 s; unsigned int w[4]; } pk;
                    pk.w[0] = cvt_pk_bf16(f0.x, f0.y);
                    pk.w[1] = cvt_pk_bf16(f0.z, f0.w);
                    pk.w[2] = cvt_pk_bf16(f1.x, f1.y);
                    pk.w[3] = cvt_pk_bf16(f1.z, f1.w);
                    v = pk.s;
                } else {
                    v = *reinterpret_cast<const s16x8*>(
                        A1 + (size_t)(row0 + r) * K1 + gk);
                }
            } else {
                v = *reinterpret_cast<const s16x8*>(
                    A2 + (size_t)(row0 + r) * K2 + (gk - K1));
            }
            *reinterpret_cast<s16x8*>(&As[r * 128 + ((c ^ (r & 7)) << 3)]) = v;
            s16x8 wv = *reinterpret_cast<const s16x8*>(
                W + (size_t)(cb + r) * K + kc + c * 8);
            *reinterpret_cast<s16x8*>(&Ws[r * 128 + ((c ^ (r & 7)) << 3)]) = wv;
        }
        __syncthreads();
#pragma unroll
        for (int ks = 0; ks < 4; ++ks) {
            int c = ks * 4 + lg;
            s16x8 af[4], bf[4];
#pragma unroll
            for (int i = 0; i < 4; ++i) {
                int r = wm * 64 + i * 16 + lr;
                af[i] = *reinterpret_cast<s16x8*>(&As[r * 128 + ((c ^ (r & 7)) << 3)]);
                int n = wn * 64 + i * 16 + lr;
                bf[i] = *reinterpret_cast<s16x8*>(&Ws[n * 128 + ((c ^ (n & 7)) << 3)]);
            }
#pragma unroll
            for (int mi = 0; mi < 4; ++mi)
#pragma unroll
                for (int ni = 0; ni < 4; ++ni)
                    acc[mi][ni] = __builtin_amdgcn_mfma_f32_16x16x32_bf16(
                        af[mi], bf[ni], acc[mi][ni], 0, 0, 0);
        }
        __syncthreads();
    }
#pragma unroll
    for (int mi = 0; mi < 4; ++mi) {
#pragma unroll
        for (int ni = 0; ni < 4; ++ni) {
            int colg = cb + wn * 64 + ni * 16 + lr;
            float bs = bias ? bias[colg] : 0.f;
#pragma unroll
            for (int r4 = 0; r4 < 4; ++r4) {
                int rowg = row0 + wm * 64 + mi * 16 + lg * 4 + r4;
                float v = acc[mi][ni][r4] + bs;
                if (resid) v += resid[(size_t)rowg * HIDDEN + colg];
                if (act) v = silu_f(v);
                if (Cf) Cf[(size_t)rowg * ldC + colg] = v;
                if (Cb) Cb[(size_t)rowg * ldC + colg] = f2bf(v);
            }
        }
    }
}

// ---------------- fused node MLP: h = hn + silu([hn|mag]@W1^T+b1)@W2^T + b2
__global__ __launch_bounds__(256) void nmlp(
    const unsigned short* __restrict__ hnbf,
    const unsigned short* __restrict__ magbf,
    const unsigned short* __restrict__ w1,   // [128][256] bf16
    const float* __restrict__ b1,
    const unsigned short* __restrict__ w2,   // [128][128] bf16
    const float* __restrict__ b2,
    const float* __restrict__ hnf,           // resid fp32 [M,128]
    float* __restrict__ hout,
    unsigned short* __restrict__ houtbf) {
    __shared__ __align__(16) unsigned short As[128 * 128];
    __shared__ __align__(16) unsigned short Ws[128 * 128];
    int tid = threadIdx.x;
    int wid = tid >> 6, l = tid & 63, lr = l & 15, lg = l >> 4;
    int wm = wid >> 1, wn = wid & 1;
    int row0 = blockIdx.x * 128;
    f32x4 acc[4][4];
#pragma unroll
    for (int i = 0; i < 4; ++i)
#pragma unroll
        for (int j = 0; j < 4; ++j) {
            f32x4 z = { 0.f, 0.f, 0.f, 0.f };
            acc[i][j] = z;
        }

    // ---- stage 1: t = silu([hn | mag] @ W1^T + b1)
    for (int kc = 0; kc < 2; ++kc) {
        const unsigned short* Xsrc = kc ? magbf : hnbf;
#pragma unroll
        for (int jj = 0; jj < 8; ++jj) {
            int j = tid + jj * 256;
            int r = j >> 4, c = j & 15;
            s16x8 v = *reinterpret_cast<const s16x8*>(
                Xsrc + (size_t)(row0 + r) * 128 + c * 8);
            *reinterpret_cast<s16x8*>(&As[r * 128 + ((c ^ (r & 7)) << 3)]) = v;
            s16x8 wv = *reinterpret_cast<const s16x8*>(
                w1 + (size_t)r * 256 + kc * 128 + c * 8);
            *reinterpret_cast<s16x8*>(&Ws[r * 128 + ((c ^ (r & 7)) << 3)]) = wv;
        }
        __syncthreads();
#pragma unroll
        for (int ks = 0; ks < 4; ++ks) {
            int c = ks * 4 + lg;
            s16x8 af[4], bf[4];
#pragma unroll
            for (int i = 0; i < 4; ++i) {
                int r = wm * 64 + i * 16 + lr;
                af[i] = *reinterpret_cast<s16x8*>(&As[r * 128 + ((c ^ (r & 7)) << 3)]);
                int n = wn * 64 + i * 16 + lr;
                bf[i] = *reinterpret_cast<s16x8*>(&Ws[n * 128 + ((c ^ (n & 7)) << 3)]);
            }
#pragma unroll
            for (int mi = 0; mi < 4; ++mi)
#pragma unroll
                for (int ni = 0; ni < 4; ++ni)
                    acc[mi][ni] = __builtin_amdgcn_mfma_f32_16x16x32_bf16(
                        af[mi], bf[ni], acc[mi][ni], 0, 0, 0);
        }
        __syncthreads();
    }

    // ---- t -> As (swizzled bf16), stage W2 -> Ws
#pragma unroll
    for (int ni = 0; ni < 4; ++ni) {
        int col = wn * 64 + ni * 16 + lr;
        float bs = b1[col];
        int cc = col >> 3, cin = col & 7;
#pragma unroll
        for (int mi = 0; mi < 4; ++mi) {
#pragma unroll
            for (int r4 = 0; r4 < 4; ++r4) {
                int rl = wm * 64 + mi * 16 + lg * 4 + r4;
                float tv = silu_f(acc[mi][ni][r4] + bs);
                As[rl * 128 + ((cc ^ (rl & 7)) << 3) + cin] = f2bf(tv);
                acc[mi][ni][r4] = 0.f;
            }
        }
    }
#pragma unroll
    for (int jj = 0; jj < 8; ++jj) {
        int j = tid + jj * 256;
        int r = j >> 4, c = j & 15;
        s16x8 wv = *reinterpret_cast<const s16x8*>(w2 + (size_t)r * 128 + c * 8);
        *reinterpret_cast<s16x8*>(&Ws[r * 128 + ((c ^ (r & 7)) << 3)]) = wv;
    }
    __syncthreads();

    // ---- stage 2: out = t @ W2^T
#pragma unroll
    for (int ks = 0; ks < 4; ++ks) {
        int c = ks * 4 + lg;
        s16x8 af[4], bf[4];
#pragma unroll
        for (int i = 0; i < 4; ++i) {
            int r = wm * 64 + i * 16 + lr;
            af[i] = *reinterpret_cast<s16x8*>(&As[r * 128 + ((c ^ (r & 7)) << 3)]);
            int n = wn * 64 + i * 16 + lr;
            bf[i] = *reinterpret_cast<s16x8*>(&Ws[n * 128 + ((c ^ (n & 7)) << 3)]);
        }
#pragma unroll
        for (int mi = 0; mi < 4; ++mi)
#pragma unroll
            for (int ni = 0; ni < 4; ++ni)
                acc[mi][ni] = __builtin_amdgcn_mfma_f32_16x16x32_bf16(
                    af[mi], bf[ni], acc[mi][ni], 0, 0, 0);
    }

    // ---- epilogue: + b2 + resid
#pragma unroll
    for (int ni = 0; ni < 4; ++ni) {
        int colg = wn * 64 + ni * 16 + lr;
        float bs = b2[colg];
#pragma unroll
        for (int mi = 0; mi < 4; ++mi) {
#pragma unroll
            for (int r4 = 0; r4 < 4; ++r4) {
                int rowg = row0 + wm * 64 + mi * 16 + lg * 4 + r4;
                float v = acc[mi][ni][r4] + bs + hnf[(size_t)rowg * HIDDEN + colg];
                hout[(size_t)rowg * HIDDEN + colg] = v;
                if (houtbf) houtbf[(size_t)rowg * HIDDEN + colg] = f2bf(v);
            }
        }
    }
}

// ---------------- edge MLP + in-register segmented mean ----------------
__global__ __launch_bounds__(256) void edge_mfma2(
    const unsigned short* __restrict__ ABbf,
    const int* __restrict__ colv,
    const int* __restrict__ rp, const float* __restrict__ dist,
    const unsigned short* __restrict__ w2bf, const float* __restrict__ wdl,
    const float* __restrict__ eb2l, unsigned short* __restrict__ magbf, int N) {
    __shared__ __align__(16) unsigned short m1[72 * 128];
    __shared__ __align__(8) float wds[128];
    __shared__ int rpl[5];
    int tid = threadIdx.x;
    int v0 = blockIdx.x * 4;
    if (tid < 5) rpl[tid] = rp[v0 + tid];
    if (tid >= 64 && tid < 192) wds[tid - 64] = wdl[tid - 64];

    int wid = tid >> 6, l = tid & 63, lr = l & 15, lg = l >> 4;
    int nb = wid * 32;
    s16x8 wfr[4][2];
#pragma unroll
    for (int ks = 0; ks < 4; ++ks)
#pragma unroll
        for (int ni = 0; ni < 2; ++ni) {
            int n = nb + ni * 16 + lr;
            wfr[ks][ni] = *reinterpret_cast<const s16x8*>(
                w2bf + (size_t)n * 128 + (ks * 4 + lg) * 8);
        }
    __syncthreads();

    int t0 = rpl[0];
    int nE = rpl[4] - t0;
    if (nE > 72) nE = 72;
    int nC = (nE + 15) >> 4;
    int o1 = rpl[1] - t0, o2 = rpl[2] - t0, o3 = rpl[3] - t0;

    // Build m1 = silu(A[u] + (B[v]+eb1) + d*wd) as bf16, swizzled.
    const float2* wds2 = reinterpret_cast<const float2*>(wds);
    for (int i = tid; i < nE * 16; i += 256) {
        int r = i >> 4, c = i & 15;
        int t = t0 + r;
        int u = colv[t];
        int seg = (r >= o1) + (r >= o2) + (r >= o3);
        float d = dist[t];
        union { s16x8 s; unsigned int w[4]; } av, bv, pk;
        av.s = *reinterpret_cast<const s16x8*>(ABbf + (size_t)u * 256 + c * 8);
        bv.s = *reinterpret_cast<const s16x8*>(
            ABbf + (size_t)(v0 + seg) * 256 + 128 + c * 8);
#pragma unroll
        for (int j = 0; j < 4; ++j) {
            float a0 = __uint_as_float(av.w[j] << 16);
            float a1 = __uint_as_float(av.w[j] & 0xffff0000u);
            float b0 = __uint_as_float(bv.w[j] << 16);
            float b1 = __uint_as_float(bv.w[j] & 0xffff0000u);
            float2 wp = wds2[c * 4 + j];
            float s0 = silu_f(a0 + b0 + d * wp.x);
            float s1 = silu_f(a1 + b1 + d * wp.y);
            pk.w[j] = cvt_pk_bf16(s0, s1);
        }
        *reinterpret_cast<s16x8*>(&m1[r * 128 + ((c ^ (r & 7)) << 3)]) = pk.s;
    }
    __syncthreads();

    f32x4 acc[5][2];
#pragma unroll
    for (int mc = 0; mc < 5; ++mc)
#pragma unroll
        for (int f = 0; f < 2; ++f) {
            f32x4 z = { 0.f, 0.f, 0.f, 0.f };
            acc[mc][f] = z;
        }
#pragma unroll
    for (int ks = 0; ks < 4; ++ks) {
        int c = ks * 4 + lg;
#pragma unroll
        for (int mc = 0; mc < 5; ++mc) {
            if (mc < nC) {
                int r = mc * 16 + lr;
                int rc = (r < nE) ? r : 0;
                s16x8 af = *reinterpret_cast<s16x8*>(
                    &m1[rc * 128 + ((c ^ (rc & 7)) << 3)]);
                acc[mc][0] = __builtin_amdgcn_mfma_f32_16x16x32_bf16(
                    af, wfr[ks][0], acc[mc][0], 0, 0, 0);
                acc[mc][1] = __builtin_amdgcn_mfma_f32_16x16x32_bf16(
                    af, wfr[ks][1], acc[mc][1], 0, 0, 0);
            }
        }
    }

    // silu(acc + eb2) and segmented mean, in-register.
    float e20 = eb2l[nb + lr], e21 = eb2l[nb + 16 + lr];
    float mac[2][4];
#pragma unroll
    for (int f = 0; f < 2; ++f)
#pragma unroll
        for (int nd = 0; nd < 4; ++nd) mac[f][nd] = 0.f;
#pragma unroll
    for (int mc = 0; mc < 5; ++mc) {
        if (mc < nC) {
#pragma unroll
            for (int r4 = 0; r4 < 4; ++r4) {
                int r = mc * 16 + lg * 4 + r4;
                bool vd = r < nE;
                bool s0 = vd & (r < o1);
                bool s1 = vd & (r >= o1) & (r < o2);
                bool s2 = vd & (r >= o2) & (r < o3);
                bool s3 = vd & (r >= o3);
                float sv0 = silu_f(acc[mc][0][r4] + e20);
                float sv1 = silu_f(acc[mc][1][r4] + e21);
                mac[0][0] += s0 ? sv0 : 0.f;
                mac[0][1] += s1 ? sv0 : 0.f;
                mac[0][2] += s2 ? sv0 : 0.f;
                mac[0][3] += s3 ? sv0 : 0.f;
                mac[1][0] += s0 ? sv1 : 0.f;
                mac[1][1] += s1 ? sv1 : 0.f;
                mac[1][2] += s2 ? sv1 : 0.f;
                mac[1][3] += s3 ? sv1 : 0.f;
            }
        }
    }
#pragma unroll
    for (int f = 0; f < 2; ++f)
#pragma unroll
        for (int nd = 0; nd < 4; ++nd) {
            float x = mac[f][nd];
            x += __shfl_xor(x, 16, 64);
            x += __shfl_xor(x, 32, 64);
            mac[f][nd] = x;
        }
    float c0 = (float)(rpl[1] - rpl[0]);
    float c1 = (float)(rpl[2] - rpl[1]);
    float c2 = (float)(rpl[3] - rpl[2]);
    float c3 = (float)(rpl[4] - rpl[3]);
    float iv0 = c0 > 0.f ? 1.f / c0 : 0.f;
    float iv1 = c1 > 0.f ? 1.f / c1 : 0.f;
    float iv2 = c2 > 0.f ? 1.f / c2 : 0.f;
    float iv3 = c3 > 0.f ? 1.f / c3 : 0.f;
    float sel0 = (lg == 0) ? mac[0][0] : (lg == 1) ? mac[0][1]
               : (lg == 2) ? mac[0][2] : mac[0][3];
    float sel1 = (lg == 0) ? mac[1][0] : (lg == 1) ? mac[1][1]
               : (lg == 2) ? mac[1][2] : mac[1][3];
    float ivn  = (lg == 0) ? iv0 : (lg == 1) ? iv1 : (lg == 2) ? iv2 : iv3;
    magbf[(size_t)(v0 + lg) * HIDDEN + nb + lr] = f2bf(sel0 * ivn);
    magbf[(size_t)(v0 + lg) * HIDDEN + nb + 16 + lr] = f2bf(sel1 * ivn);
}

extern "C" void kernel_launch(void* const* d_in, const int* in_sizes, int n_in,
                              void* d_out, int out_size, void* d_ws, size_t ws_size,
                              hipStream_t stream) {
    const float* y     = (const float*)d_in[0];
    const float* gc    = (const float*)d_in[1];
    const int*   eidx  = (const int*)d_in[2];
    const float* W_in  = (const float*)d_in[3];
    const float* b_in  = (const float*)d_in[4];
    const float* gam   = (const float*)d_in[5];
    const float* bet   = (const float*)d_in[6];
    const float* eW1   = (const float*)d_in[7];
    const float* eb1   = (const float*)d_in[8];
    const float* eW2   = (const float*)d_in[9];
    const float* eb2   = (const float*)d_in[10];
    const float* nW1   = (const float*)d_in[11];
    const float* nb1   = (const float*)d_in[12];
    const float* nW2   = (const float*)d_in[13];
    const float* nb2   = (const float*)d_in[14];
    const float* W_out = (const float*)d_in[15];
    const float* b_out = (const float*)d_in[16];

    const int CODE = in_sizes[16];          // 1024
    const int M = in_sizes[0] / CODE;       // 32768 nodes
    const int E = in_sizes[2] / 2;

    float* out = (float*)d_out;

    char* ws = (char*)d_ws;
    size_t off = 0;
    auto carve = [&](size_t bytes) {
        char* p = ws + off;
        off += (bytes + 255) & ~(size_t)255;
        return p;
    };
    float*          buf_h   = (float*)carve((size_t)M * HIDDEN * 4);
    float*          buf_hn  = (float*)carve((size_t)M * HIDDEN * 4);
    unsigned short* hnbf    = (unsigned short*)carve((size_t)M * HIDDEN * 2);
    unsigned short* ABbf    = (unsigned short*)carve((size_t)M * 256 * 2);
    unsigned short* magbf   = (unsigned short*)carve((size_t)M * HIDDEN * 2);
    unsigned short* hbf     = (unsigned short*)carve((size_t)M * HIDDEN * 2);
    int*            row_ptr = (int*)carve((size_t)(M + 1) * 4);
    float*          dist    = (float*)carve((size_t)E * 4);
    unsigned short* winbf   = (unsigned short*)carve((size_t)HIDDEN * CODE * 2);
    unsigned short* woutbf  = (unsigned short*)carve((size_t)CODE * HIDDEN * 2);
    unsigned short* wn1bf   = (unsigned short*)carve((size_t)NLAYERS * HIDDEN * 256 * 2);
    unsigned short* wn2bf   = (unsigned short*)carve((size_t)NLAYERS * HIDDEN * HIDDEN * 2);
    unsigned short* w2bf    = (unsigned short*)carve((size_t)NLAYERS * HIDDEN * HIDDEN * 2);
    unsigned short* w1ab    = (unsigned short*)carve((size_t)NLAYERS * 256 * HIDDEN * 2);
    float*          bias256 = (float*)carve((size_t)NLAYERS * 256 * 4);
    float*          wdl     = (float*)carve((size_t)NLAYERS * HIDDEN * 4);

    const int* row  = eidx;
    const int* colA = eidx + E;

    rowptr_kernel<<<dim3((M + 1 + 255) / 256), 256, 0, stream>>>(row, E, M, row_ptr);
    dist_kernel<<<dim3((E + 255) / 256), 256, 0, stream>>>(row, colA, gc, dist, E);

    conv_kernel<<<dim3(HIDDEN * CODE / 1024), 256, 0, stream>>>(W_in, winbf, HIDDEN * CODE);
    conv_kernel<<<dim3(CODE * HIDDEN / 1024), 256, 0, stream>>>(W_out, woutbf, CODE * HIDDEN);
    conv_kernel<<<dim3(NLAYERS * HIDDEN * 256 / 1024), 256, 0, stream>>>(
        nW1, wn1bf, NLAYERS * HIDDEN * 256);
    conv_kernel<<<dim3(NLAYERS * HIDDEN * HIDDEN / 1024), 256, 0, stream>>>(
        nW2, wn2bf, NLAYERS * HIDDEN * HIDDEN);
    conv_kernel<<<dim3(NLAYERS * HIDDEN * HIDDEN / 1024), 256, 0, stream>>>(
        eW2, w2bf, NLAYERS * HIDDEN * HIDDEN);
    pack_kernel<<<dim3(NLAYERS), 256, 0, stream>>>(eW1, eb1, w1ab, bias256, wdl);

    // h = y @ W_in^T + b_in (fp32 A converted in staging)
    mgemm<<<dim3(M / 128, 1), 256, 0, stream>>>(
        nullptr, y, CODE, nullptr, 0, winbf, b_in, nullptr, buf_h, nullptr, HIDDEN, 0);

    for (int l = 0; l < NLAYERS; ++l) {
        const float* eb2l = eb2 + (size_t)l * HIDDEN;
        const float* nb1l = nb1 + (size_t)l * HIDDEN;
        const float* nb2l = nb2 + (size_t)l * HIDDEN;

        ln_kernel<<<dim3(M / 4), 256, 0, stream>>>(
            buf_h, gam + (size_t)l * HIDDEN, bet + (size_t)l * HIDDEN,
            buf_hn, hnbf, M);

        // [A|B] = hn @ w1ab^T + bias256 (B part has +eb1), bf16 out
        mgemm<<<dim3(M / 128, 2), 256, 0, stream>>>(
            hnbf, nullptr, HIDDEN, nullptr, 0,
            w1ab + (size_t)l * 256 * HIDDEN, bias256 + (size_t)l * 256,
            nullptr, nullptr, ABbf, 256, 0);

        edge_mfma2<<<dim3(M / 4), 256, 0, stream>>>(
            ABbf, colA, row_ptr, dist,
            w2bf + (size_t)l * HIDDEN * HIDDEN, wdl + (size_t)l * HIDDEN,
            eb2l, magbf, M);

        // fused node MLP: h = hn + silu([hn|mag]@W1^T+b1)@W2^T + b2
        nmlp<<<dim3(M / 128), 256, 0, stream>>>(
            hnbf, magbf,
            wn1bf + (size_t)l * HIDDEN * 256, nb1l,
            wn2bf + (size_t)l * HIDDEN * HIDDEN, nb2l,
            buf_hn, buf_h, (l == NLAYERS - 1) ? hbf : nullptr);
    }

    // out = h @ W_out^T + b_out
    mgemm<<<dim3(M / 128, CODE / 128), 256, 0, stream>>>(
        hbf, nullptr, HIDDEN, nullptr, 0, woutbf, b_out,
        nullptr, out, nullptr, CODE, 0);
}